// Round 1
// baseline (48.090 us; speedup 1.0000x reference)
//
#include <hip/hip_runtime.h>

// out[b,d,s] = x[b,d,s] + sum_f phase_one_hot[b,f,s] * emb_weight[f,d]
// B=16, F=9, S=4096, D=512. Pure streaming op: memory-bound.

#define PE_B 16
#define PE_F 9
#define PE_S 4096
#define PE_D 512
#define PE_DPER 8        // d values per thread: amortizes the 9 p-loads
#define PE_BLOCK 256

__global__ __launch_bounds__(PE_BLOCK) void PhaseEncoding_46918222742189_kernel(
    const float* __restrict__ x,
    const float* __restrict__ p,
    const float* __restrict__ w,
    float* __restrict__ out)
{
    // grid: x = S/4/PE_BLOCK (s-chunks), y = D/PE_DPER, z = B
    const int tid = threadIdx.x;
    const int s4  = blockIdx.x * PE_BLOCK + tid;   // float4 index along s
    const int s   = s4 * 4;
    const int d0  = blockIdx.y * PE_DPER;
    const int b   = blockIdx.z;

    // Load p[b, f, s..s+3] for all 9 f into registers (coalesced float4 loads;
    // p is 2.4 MB total -> L2-resident for the 64x re-reads across d-groups).
    float4 pv[PE_F];
    const float* pb = p + ((size_t)b * PE_F) * PE_S + s;
#pragma unroll
    for (int f = 0; f < PE_F; ++f)
        pv[f] = *reinterpret_cast<const float4*>(pb + (size_t)f * PE_S);

    const float* xb = x   + ((size_t)b * PE_D + d0) * PE_S + s;
    float*       ob = out + ((size_t)b * PE_D + d0) * PE_S + s;

#pragma unroll
    for (int k = 0; k < PE_DPER; ++k) {
        const int d = d0 + k;
        float4 xv = *reinterpret_cast<const float4*>(xb + (size_t)k * PE_S);
        float a0 = 0.f, a1 = 0.f, a2 = 0.f, a3 = 0.f;
#pragma unroll
        for (int f = 0; f < PE_F; ++f) {
            // wave-uniform index (no threadIdx) -> scalar load, L1/K$ cached
            const float wv = w[f * PE_D + d];
            a0 = fmaf(pv[f].x, wv, a0);
            a1 = fmaf(pv[f].y, wv, a1);
            a2 = fmaf(pv[f].z, wv, a2);
            a3 = fmaf(pv[f].w, wv, a3);
        }
        float4 ov = make_float4(xv.x + a0, xv.y + a1, xv.z + a2, xv.w + a3);
        *reinterpret_cast<float4*>(ob + (size_t)k * PE_S) = ov;
    }
}

extern "C" void kernel_launch(void* const* d_in, const int* in_sizes, int n_in,
                              void* d_out, int out_size, void* d_ws, size_t ws_size,
                              hipStream_t stream) {
    const float* x = (const float*)d_in[0];   // (B, D, S) f32
    const float* p = (const float*)d_in[1];   // (B, F, S) f32
    const float* w = (const float*)d_in[2];   // (F, D)   f32
    float* out = (float*)d_out;               // (B, D, S) f32

    dim3 grid(PE_S / 4 / PE_BLOCK,   // 4 s-chunks
              PE_D / PE_DPER,        // 64 d-groups
              PE_B);                 // 16 batches
    PhaseEncoding_46918222742189_kernel<<<grid, dim3(PE_BLOCK), 0, stream>>>(x, p, w, out);
}

// Round 2
// 44.664 us; speedup vs baseline: 1.0767x; 1.0767x over previous
//
#include <hip/hip_runtime.h>

// out[b,d,s] = x[b,d,s] + sum_f phase_one_hot[b,f,s] * emb_weight[f,d]
// B=16, F=9, S=4096, D=512. Memory-bound streaming op.
//
// R1 -> R2 changes:
//  - hoist all 8 x float4 loads ahead of compute (8 outstanding VMEM/thread;
//    R1's VGPR=36 proved the compiler had serialized them)
//  - nontemporal stores for out (write-once data must not evict x from the
//    256MB L3; x+p = 136MB fits entirely -> replay fetches go to ~0)

#define PE_B 16
#define PE_F 9
#define PE_S 4096
#define PE_D 512
#define PE_DPER 8
#define PE_BLOCK 256

typedef float f32x4 __attribute__((ext_vector_type(4)));

__global__ __launch_bounds__(PE_BLOCK) void PhaseEncoding_46918222742189_kernel(
    const float* __restrict__ x,
    const float* __restrict__ p,
    const float* __restrict__ w,
    float* __restrict__ out)
{
    // grid: x = S/4/PE_BLOCK (s-chunks), y = D/PE_DPER, z = B
    const int tid = threadIdx.x;
    const int s   = (blockIdx.x * PE_BLOCK + tid) * 4;  // first s of this thread's float4
    const int d0  = blockIdx.y * PE_DPER;
    const int b   = blockIdx.z;

    const float* pb = p   + ((size_t)b * PE_F) * PE_S + s;
    const float* xb = x   + ((size_t)b * PE_D + d0) * PE_S + s;
    float*       ob = out + ((size_t)b * PE_D + d0) * PE_S + s;

    // p[b, f, s..s+3] for all 9 f (coalesced; p is 2.4MB -> L2/L3 resident)
    f32x4 pv[PE_F];
#pragma unroll
    for (int f = 0; f < PE_F; ++f)
        pv[f] = *reinterpret_cast<const f32x4*>(pb + (size_t)f * PE_S);

    // all 8 x vectors issued back-to-back: 8 outstanding HBM loads/thread
    f32x4 xv[PE_DPER];
#pragma unroll
    for (int k = 0; k < PE_DPER; ++k)
        xv[k] = *reinterpret_cast<const f32x4*>(xb + (size_t)k * PE_S);

#pragma unroll
    for (int k = 0; k < PE_DPER; ++k) {
        const int d = d0 + k;
        float a0 = xv[k].x, a1 = xv[k].y, a2 = xv[k].z, a3 = xv[k].w;
#pragma unroll
        for (int f = 0; f < PE_F; ++f) {
            // wave-uniform index -> scalar load via constant cache, ~free
            const float wv = w[f * PE_D + d];
            a0 = fmaf(pv[f].x, wv, a0);
            a1 = fmaf(pv[f].y, wv, a1);
            a2 = fmaf(pv[f].z, wv, a2);
            a3 = fmaf(pv[f].w, wv, a3);
        }
        f32x4 ov = {a0, a1, a2, a3};
        // write-once data: nt store, don't pollute L3
        __builtin_nontemporal_store(ov, reinterpret_cast<f32x4*>(ob + (size_t)k * PE_S));
    }
}

extern "C" void kernel_launch(void* const* d_in, const int* in_sizes, int n_in,
                              void* d_out, int out_size, void* d_ws, size_t ws_size,
                              hipStream_t stream) {
    const float* x = (const float*)d_in[0];   // (B, D, S) f32
    const float* p = (const float*)d_in[1];   // (B, F, S) f32
    const float* w = (const float*)d_in[2];   // (F, D)   f32
    float* out = (float*)d_out;               // (B, D, S) f32

    dim3 grid(PE_S / 4 / PE_BLOCK,   // 4 s-chunks
              PE_D / PE_DPER,        // 64 d-groups
              PE_B);                 // 16 batches
    PhaseEncoding_46918222742189_kernel<<<grid, dim3(PE_BLOCK), 0, stream>>>(x, p, w, out);
}